// Round 7
// baseline (478.341 us; speedup 1.0000x reference)
//
#include <hip/hip_runtime.h>
#include <cfloat>

// Problem constants (B=8, S=2048, D=256, K=8192)
#define N_TOK 16384
#define DIM 256
#define KCB 8192
#define BETA_C 0.25f
#define SLAB 4096
#define NSLAB 4
#define NSPLIT 32          // 8192 / 256 cols per block

typedef __attribute__((ext_vector_type(8))) short short8;   // 8 bf16 (4 VGPRs)
typedef __attribute__((ext_vector_type(4))) float f32x4;    // MFMA acc
typedef unsigned short ushort_t;

__device__ __forceinline__ void async_copy16(const void* g, void* l) {
    __builtin_amdgcn_global_load_lds(
        (const __attribute__((address_space(1))) unsigned int*)g,
        (__attribute__((address_space(3))) unsigned int*)l, 16, 0, 0);
}

// top-2 merge with lowest-index tie-break (R4-proven logic)
__device__ __forceinline__ void merge2(float& v1, int& i1, float& v2, int& i2,
                                       float b1, int j1, float b2, int j2) {
    const bool bf_ = (b1 < v1) || (b1 == v1 && j1 < i1);
    const float nv1 = bf_ ? b1 : v1; const int ni1 = bf_ ? j1 : i1;
    const float c = bf_ ? v1 : b1;   const int ci = bf_ ? i1 : j1;
    const float d = bf_ ? b2 : v2;   const int di = bf_ ? j2 : i2;
    const bool ds_ = (d < c) || (d == c && di < ci);
    v1 = nv1; i1 = ni1;
    v2 = ds_ ? d : c; i2 = ds_ ? di : ci;
}

// ---------------- prep: f32 row -> packed bf16 [hi(256) | lo(256)] (+ norm) -------
template <int WITH_NORM>
__global__ void __launch_bounds__(256)
prep2_kernel(const float* __restrict__ src, ushort_t* __restrict__ dst,
             float* __restrict__ norm, int nrows) {
    const int w = threadIdx.x >> 6, lane = threadIdx.x & 63;
    const int r = blockIdx.x * 4 + w;
    if (r >= nrows) return;
    const float4 v = *reinterpret_cast<const float4*>(src + (size_t)r * DIM + lane * 4);
    const float vv[4] = {v.x, v.y, v.z, v.w};
    unsigned hw[2], lw[2];
    float s = 0.f;
#pragma unroll
    for (int j = 0; j < 2; ++j) {
        unsigned h0, h1, l0, l1;
        {
            const float f = vv[2 * j];
            s += f * f;
            const unsigned u = __float_as_uint(f);
            h0 = u >> 16;
            l0 = __float_as_uint(f - __uint_as_float(u & 0xFFFF0000u)) >> 16;
        }
        {
            const float f = vv[2 * j + 1];
            s += f * f;
            const unsigned u = __float_as_uint(f);
            h1 = u >> 16;
            l1 = __float_as_uint(f - __uint_as_float(u & 0xFFFF0000u)) >> 16;
        }
        hw[j] = h0 | (h1 << 16);
        lw[j] = l0 | (l1 << 16);
    }
    ushort_t* row = dst + (size_t)r * 512;
    *reinterpret_cast<uint2*>(row + lane * 4) = make_uint2(hw[0], hw[1]);
    *reinterpret_cast<uint2*>(row + 256 + lane * 4) = make_uint2(lw[0], lw[1]);
    if (WITH_NORM) {
#pragma unroll
        for (int o = 32; o > 0; o >>= 1) s += __shfl_down(s, o, 64);
        if (lane == 0) norm[r] = s;
    }
}

// ---------------- W transpose to bf16: WT[e][d] = bf16(W[d][e]) ----------------
__global__ void wt_kernel(const float* __restrict__ W, ushort_t* __restrict__ WT) {
    const int flat = blockIdx.x * 256 + threadIdx.x;
    const int d = flat >> 8, e = flat & 255;
    WT[(size_t)e * 256 + d] = (ushort_t)(__float_as_uint(W[flat]) >> 16);
}

// ---------------- pipelined MFMA distance GEMM (256x256 tile, counted vmcnt) -----
// Block: 256 slab rows x 256 codes, virtual K=768 (3 bf16-split passes x D=256).
// dist = ||e||^2 - 2*x.e (row-const ||x||^2 dropped). Top-2 epilogue once/block.
// Register plan (R7): 512-thr block = 2 waves/SIMD = 256 regs/lane hard budget.
// acc[8][4] = 128 AGPR; arch-VGPR side must stay < 128 -> per-K-step runs 4
// phases of 16 MFMA: B-frags (32 regs) held all step, A-frags in a 2-deep
// rotating block (16+16), counted lgkmcnt(4) between phases. Peak ~90 arch.
__global__ void __launch_bounds__(512, 1)
dist_kernel(const ushort_t* __restrict__ X2, const ushort_t* __restrict__ E2,
            const float* __restrict__ enorm, uint4* __restrict__ mg) {
    __shared__ char sb[131072];   // A: [buf][256][128B] @0/32K; B: @64K/96K

    const int tid = threadIdx.x;
    const int lane = tid & 63;
    const int w = tid >> 6;             // 0..7
    const int wy = w >> 2, wx = w & 3;  // 2x4 wave grid; wave tile 128x64
    const int l15 = lane & 15, l4 = lane >> 4;
    const int rr = lane >> 3, egr = (lane & 7) ^ rr;  // pre-swizzled source granule

    // XCD-chunked bijective swizzle of 512 blocks (16 row x 32 col)
    const int bid = blockIdx.x;
    const int sw = (bid & 7) * 64 + (bid >> 3);
    const int bx = sw & 15, by = sw >> 4;
    const int row0 = bx * 256;          // slab-local token row
    const int col0 = by * 256;          // global code col

    const ushort_t* Asrc = X2 + (size_t)(row0 + rr) * 512 + egr * 8;
    const ushort_t* Bsrc = E2 + (size_t)(col0 + rr) * 512 + egr * 8;

    // per-thread swizzled ds_read base offsets; frag adds m*2048 (16 rows)
    int offA[2], offB[2];
#pragma unroll
    for (int ks = 0; ks < 2; ++ks) {
        offA[ks] = (wy * 128 + l15) * 128 + ((ks * 64 + l4 * 16) ^ ((l15 & 7) << 4));
        offB[ks] = (wx * 64 + l15) * 128 + ((ks * 64 + l4 * 16) ^ ((l15 & 7) << 4));
    }

    f32x4 acc[8][4];
#pragma unroll
    for (int m = 0; m < 8; ++m)
#pragma unroll
        for (int n = 0; n < 4; ++n) { f32x4 z = {0.f, 0.f, 0.f, 0.f}; acc[m][n] = z; }

    // step s (0..11) -> pass p=s>>2 (hh,lh,hl), d-quarter dq=s&3
    auto stage = [&](int sidx, int buf_) {
        const int aoff = (((sidx >> 2) == 1) ? 256 : 0) + (sidx & 3) * 64;
        const int boff = (((sidx >> 2) == 2) ? 256 : 0) + (sidx & 3) * 64;
#pragma unroll
        for (int i = 0; i < 4; ++i) {
            const int g = w * 4 + i;    // 8-row granule
            async_copy16(Asrc + (size_t)g * 4096 + aoff, sb + buf_ * 32768 + g * 1024);
            async_copy16(Bsrc + (size_t)g * 4096 + boff, sb + 65536 + buf_ * 32768 + g * 1024);
        }
    };

    // prologue: steps 0,1 in flight; wait own step-0 loads (in-order retire)
    stage(0, 0);
    stage(1, 1);
    asm volatile("s_waitcnt vmcnt(8)" ::: "memory");
    __builtin_amdgcn_s_barrier();

#pragma unroll
    for (int s = 0; s < 12; ++s) {
        const int buf = s & 1;
        const char* Al = sb + buf * 32768;
        const char* Bl = sb + 65536 + buf * 32768;

        // B-frags (8 b128, held all step) + A phase-0 frags (4 b128)
        short8 bfr[4][2], a_cur[2][2], a_nxt[2][2];
#pragma unroll
        for (int n = 0; n < 4; ++n)
#pragma unroll
            for (int ks = 0; ks < 2; ++ks)
                bfr[n][ks] = *reinterpret_cast<const short8*>(Bl + offB[ks] + n * 2048);
#pragma unroll
        for (int mi = 0; mi < 2; ++mi)
#pragma unroll
            for (int ks = 0; ks < 2; ++ks)
                a_cur[mi][ks] = *reinterpret_cast<const short8*>(Al + offA[ks] + mi * 2048);

#pragma unroll
        for (int q = 0; q < 4; ++q) {
            // prefetch next phase's A-frags (4 b128) before waiting on current's
            if (q < 3) {
#pragma unroll
                for (int mi = 0; mi < 2; ++mi)
#pragma unroll
                    for (int ks = 0; ks < 2; ++ks)
                        a_nxt[mi][ks] = *reinterpret_cast<const short8*>(
                            Al + offA[ks] + ((q + 1) * 2 + mi) * 2048);
                asm volatile("s_waitcnt lgkmcnt(4)" ::: "memory");  // B + A(q) done
            } else {
                asm volatile("s_waitcnt lgkmcnt(0)" ::: "memory");
            }
            __builtin_amdgcn_sched_barrier(0);

            if (q == 3) {
                // all waves' reads of buf are complete -> safe to restage it
                __builtin_amdgcn_s_barrier();
                if (s + 2 < 12) stage(s + 2, buf);
                __builtin_amdgcn_sched_barrier(0);
            }

            __builtin_amdgcn_s_setprio(1);
#pragma unroll
            for (int ks = 0; ks < 2; ++ks)
#pragma unroll
                for (int mi = 0; mi < 2; ++mi)
#pragma unroll
                    for (int n = 0; n < 4; ++n)
                        acc[q * 2 + mi][n] = __builtin_amdgcn_mfma_f32_16x16x32_bf16(
                            a_cur[mi][ks], bfr[n][ks], acc[q * 2 + mi][n], 0, 0, 0);
            __builtin_amdgcn_s_setprio(0);
            __builtin_amdgcn_sched_barrier(0);

            if (q < 3) {
#pragma unroll
                for (int mi = 0; mi < 2; ++mi)
#pragma unroll
                    for (int ks = 0; ks < 2; ++ks)
                        a_cur[mi][ks] = a_nxt[mi][ks];   // SSA rename, no copy cost
            }
        }

        // counted wait: retire step s+1's loads, keep step s+2's in flight
        if (s == 10) asm volatile("s_waitcnt vmcnt(0)" ::: "memory");
        else if (s < 10) asm volatile("s_waitcnt vmcnt(8)" ::: "memory");
        __builtin_amdgcn_s_barrier();
    }

    // ---- epilogue: dist, per-row top-2 over the block's 256 cols ----
    float en[4];
#pragma unroll
    for (int n = 0; n < 4; ++n) en[n] = enorm[col0 + wx * 64 + n * 16 + l15];

    uint4* sm2 = reinterpret_cast<uint4*>(sb);   // [wx][256 rows], 16 KB
#pragma unroll
    for (int m = 0; m < 8; ++m)
#pragma unroll
        for (int j = 0; j < 4; ++j) {
            float v1 = FLT_MAX, v2 = FLT_MAX;
            int i1 = 0x7fffffff, i2 = 0x7fffffff;
#pragma unroll
            for (int n = 0; n < 4; ++n) {
                const float v = fmaf(-2.f, acc[m][n][j], en[n]);
                const int kg = col0 + wx * 64 + n * 16 + l15;
                if (v < v1) { v2 = v1; i2 = i1; v1 = v; i1 = kg; }
                else if (v < v2) { v2 = v; i2 = kg; }
            }
#pragma unroll
            for (int o = 1; o < 16; o <<= 1) {
                const float b1 = __shfl_xor(v1, o, 64), b2 = __shfl_xor(v2, o, 64);
                const int j1 = __shfl_xor(i1, o, 64), j2 = __shfl_xor(i2, o, 64);
                merge2(v1, i1, v2, i2, b1, j1, b2, j2);
            }
            if (l15 == 0) {
                const int row = wy * 128 + m * 16 + l4 * 4 + j;
                sm2[wx * 256 + row] = make_uint4(__float_as_uint(v1), (unsigned)i1,
                                                 __float_as_uint(v2), (unsigned)i2);
            }
        }
    __syncthreads();
    if (tid < 256) {
        float v1 = FLT_MAX, v2 = FLT_MAX;
        int i1 = 0x7fffffff, i2 = 0x7fffffff;
#pragma unroll
        for (int wx2 = 0; wx2 < 4; ++wx2) {
            const uint4 q = sm2[wx2 * 256 + tid];
            merge2(v1, i1, v2, i2, __uint_as_float(q.x), (int)q.y,
                   __uint_as_float(q.z), (int)q.w);
        }
        mg[(size_t)(row0 + tid) * NSPLIT + by] =
            make_uint4(__float_as_uint(v1), (unsigned)i1, __float_as_uint(v2), (unsigned)i2);
    }
}

// ---------------- merge stripes + exact f32 rescore ----------------
__global__ void __launch_bounds__(256)
merge_fixup_kernel(const float* __restrict__ x, const float* __restrict__ emb,
                   const uint4* __restrict__ mg, int* __restrict__ idx_out,
                   float* __restrict__ minq, int row_base) {
    const int w = threadIdx.x >> 6, lane = threadIdx.x & 63;
    const int nl = blockIdx.x * 4 + w;    // slab-local row
    const int n = row_base + nl;          // global row
    const uint4 q = mg[(size_t)nl * NSPLIT + (lane & 31)];
    float v1 = __uint_as_float(q.x), v2 = __uint_as_float(q.z);
    int i1 = (int)q.y, i2 = (int)q.w;
#pragma unroll
    for (int o = 1; o < 32; o <<= 1) {
        const float b1 = __shfl_xor(v1, o, 64), b2 = __shfl_xor(v2, o, 64);
        const int j1 = __shfl_xor(i1, o, 64), j2 = __shfl_xor(i2, o, 64);
        merge2(v1, i1, v2, i2, b1, j1, b2, j2);
    }
    const float4 xv = *reinterpret_cast<const float4*>(x + (size_t)n * DIM + lane * 4);
    float dsum[2];
    const int cand[2] = {i1, i2};
#pragma unroll
    for (int c = 0; c < 2; ++c) {
        const float4 ev = *reinterpret_cast<const float4*>(emb + (size_t)cand[c] * DIM + lane * 4);
        const float dx = xv.x - ev.x, dy = xv.y - ev.y, dz = xv.z - ev.z, dw = xv.w - ev.w;
        float s = dx * dx + dy * dy + dz * dz + dw * dw;
#pragma unroll
        for (int o = 32; o > 0; o >>= 1) s += __shfl_xor(s, o, 64);
        dsum[c] = s;
    }
    const bool take2 = (dsum[1] < dsum[0]) || (dsum[1] == dsum[0] && cand[1] < cand[0]);
    if (lane == 0) {
        idx_out[n] = take2 ? cand[1] : cand[0];
        minq[n] = take2 ? dsum[1] : dsum[0];
    }
}

// ---------------- fused MLP: z = e + W2T-gemm(relu(W1T-gemm(x-e)+b1))+b2 --------
// (R4-proven) Block: 64 rows, 4 waves; h lives only in LDS (bf16).
__global__ void __launch_bounds__(256)
fused_mlp_kernel(const float* __restrict__ x, const float* __restrict__ emb,
                 const int* __restrict__ idx, const ushort_t* __restrict__ W1T,
                 const ushort_t* __restrict__ W2T, const float* __restrict__ b1,
                 const float* __restrict__ b2, float* __restrict__ z) {
    __shared__ char sb[65536];
    __shared__ int idxs[64];

    const int tid = threadIdx.x;
    const int lane = tid & 63;
    const int w = tid >> 6;
    const int l15 = lane & 15, l4 = lane >> 4;
    const int rr = lane >> 3;
    const int egr = (lane & 7) ^ rr;
    const int row0 = blockIdx.x * 64;

    if (tid < 64) idxs[tid] = idx[row0 + tid];
    __syncthreads();

#pragma unroll
    for (int j = 0; j < 16; ++j) {
        const int flat = tid + 256 * j;
        const int r = flat >> 6;
        const int sg = flat & 63;
        const float4 xv = *reinterpret_cast<const float4*>(x + (size_t)(row0 + r) * DIM + sg * 4);
        const float4 ev = *reinterpret_cast<const float4*>(emb + (size_t)idxs[r] * DIM + sg * 4);
        const unsigned u0 = __float_as_uint(xv.x - ev.x), u1 = __float_as_uint(xv.y - ev.y);
        const unsigned u2 = __float_as_uint(xv.z - ev.z), u3 = __float_as_uint(xv.w - ev.w);
        const uint2 pk = make_uint2((u0 >> 16) | (u1 & 0xFFFF0000u),
                                    (u2 >> 16) | (u3 & 0xFFFF0000u));
        *reinterpret_cast<uint2*>(sb + r * 512 + ((sg * 8) ^ ((r & 7) << 4))) = pk;
    }

    const ushort_t* Wp[2] = {W1T, W2T};
    f32x4 acc[4][4];

    for (int layer = 0; layer < 2; ++layer) {
        const ushort_t* WT = Wp[layer];
#pragma unroll
        for (int m = 0; m < 4; ++m)
#pragma unroll
            for (int n = 0; n < 4; ++n) {
                f32x4 zz = {0.f, 0.f, 0.f, 0.f};
                acc[m][n] = zz;
            }
        for (int kc = 0; kc < 4; ++kc) {
            __syncthreads();
#pragma unroll
            for (int i = 0; i < 8; ++i) {
                const int g = w * 8 + i;
                async_copy16(WT + (size_t)(g * 8 + rr) * 256 + kc * 64 + egr * 8,
                             sb + 32768 + g * 1024);
            }
            __syncthreads();
#pragma unroll
            for (int ks = 0; ks < 2; ++ks) {
                short8 af[4], bf[4];
#pragma unroll
                for (int m = 0; m < 4; ++m) {
                    const int r = m * 16 + l15;
                    af[m] = *reinterpret_cast<const short8*>(
                        sb + r * 512 + ((((kc * 2 + ks) * 64) + l4 * 16) ^ ((r & 7) << 4)));
                }
#pragma unroll
                for (int n = 0; n < 4; ++n) {
                    const int r = w * 64 + n * 16 + l15;
                    bf[n] = *reinterpret_cast<const short8*>(
                        sb + 32768 + r * 128 + ((ks * 64 + l4 * 16) ^ ((r & 7) << 4)));
                }
#pragma unroll
                for (int m = 0; m < 4; ++m)
#pragma unroll
                    for (int n = 0; n < 4; ++n)
                        acc[m][n] = __builtin_amdgcn_mfma_f32_16x16x32_bf16(af[m], bf[n], acc[m][n], 0, 0, 0);
            }
        }

        if (layer == 0) {
            float b1v[4];
#pragma unroll
            for (int n = 0; n < 4; ++n) b1v[n] = b1[w * 64 + n * 16 + l15];
            __syncthreads();
#pragma unroll
            for (int m = 0; m < 4; ++m)
#pragma unroll
                for (int n = 0; n < 4; ++n)
#pragma unroll
                    for (int j = 0; j < 4; ++j) {
                        const int row = m * 16 + l4 * 4 + j;
                        const int col = w * 64 + n * 16 + l15;
                        const float hv = fmaxf(acc[m][n][j] + b1v[n], 0.f);
                        *reinterpret_cast<ushort_t*>(
                            sb + row * 512 + ((col * 2) ^ ((row & 7) << 4))) =
                            (ushort_t)(__float_as_uint(hv) >> 16);
                    }
            __syncthreads();
        } else {
            float b2v[4];
#pragma unroll
            for (int n = 0; n < 4; ++n) b2v[n] = b2[w * 64 + n * 16 + l15];
#pragma unroll
            for (int m = 0; m < 4; ++m)
#pragma unroll
                for (int n = 0; n < 4; ++n)
#pragma unroll
                    for (int j = 0; j < 4; ++j) {
                        const int row = m * 16 + l4 * 4 + j;
                        const int col = w * 64 + n * 16 + l15;
                        const float ev = emb[(size_t)idxs[row] * DIM + col];
                        z[(size_t)(row0 + row) * DIM + col] = acc[m][n][j] + b2v[n] + ev;
                    }
        }
    }
}

// ---------------- loss: BETA * mean(exact min dist) ----------------
__global__ void loss_kernel(const float* __restrict__ minq, float* __restrict__ loss_out) {
    const int tid = threadIdx.x;
    float s = 0.f;
    for (int i = tid; i < N_TOK; i += 256) s += minq[i];
#pragma unroll
    for (int o = 32; o > 0; o >>= 1) s += __shfl_down(s, o, 64);
    __shared__ float sbf[4];
    if ((tid & 63) == 0) sbf[tid >> 6] = s;
    __syncthreads();
    if (tid == 0) loss_out[0] = BETA_C * ((sbf[0] + sbf[1] + sbf[2] + sbf[3]) / (float)N_TOK);
}

extern "C" void kernel_launch(void* const* d_in, const int* in_sizes, int n_in,
                              void* d_out, int out_size, void* d_ws, size_t ws_size,
                              hipStream_t stream) {
    const float* x   = (const float*)d_in[0];
    const float* emb = (const float*)d_in[1];
    const float* W1  = (const float*)d_in[2];
    const float* b1  = (const float*)d_in[3];
    const float* W2  = (const float*)d_in[4];
    const float* b2  = (const float*)d_in[5];

    float* z_out = (float*)d_out;
    float* loss_out = z_out + (size_t)N_TOK * DIM;

    // workspace (15.1 MB used, all disjoint; proven budget >= 17.0 MB)
    char* ws = (char*)d_ws;
    float*    enorm = (float*)(ws);
    int*      idxb  = (int*)(ws + 32768);
    float*    minq  = (float*)(ws + 98304);
    ushort_t* W1T   = (ushort_t*)(ws + 163840);
    ushort_t* W2T   = (ushort_t*)(ws + 294912);
    ushort_t* E2    = (ushort_t*)(ws + 458752);     // [8192][512] bf16 (hi|lo)
    ushort_t* X2    = (ushort_t*)(ws + 8847360);    // [4096][512] bf16 slab
    uint4*    mg    = (uint4*)(ws + 13041664);      // [4096][32]

    hipLaunchKernelGGL((prep2_kernel<1>), dim3(KCB / 4), dim3(256), 0, stream,
                       emb, E2, enorm, KCB);
    hipLaunchKernelGGL(wt_kernel, dim3(256), dim3(256), 0, stream, W1, W1T);
    hipLaunchKernelGGL(wt_kernel, dim3(256), dim3(256), 0, stream, W2, W2T);
    for (int s = 0; s < NSLAB; ++s) {
        hipLaunchKernelGGL((prep2_kernel<0>), dim3(SLAB / 4), dim3(256), 0, stream,
                           x + (size_t)s * SLAB * DIM, X2, (float*)nullptr, SLAB);
        hipLaunchKernelGGL(dist_kernel, dim3(512), dim3(512), 0, stream,
                           X2, E2, enorm, mg);
        hipLaunchKernelGGL(merge_fixup_kernel, dim3(SLAB / 4), dim3(256), 0, stream,
                           x, emb, mg, idxb, minq, s * SLAB);
    }
    hipLaunchKernelGGL(fused_mlp_kernel, dim3(N_TOK / 64), dim3(256), 0, stream,
                       x, emb, idxb, W1T, W2T, b1, b2, z_out);
    hipLaunchKernelGGL(loss_kernel, dim3(1), dim3(256), 0, stream, minq, loss_out);
}

// Round 8
// 332.632 us; speedup vs baseline: 1.4380x; 1.4380x over previous
//
#include <hip/hip_runtime.h>
#include <cfloat>

// Problem constants (B=8, S=2048, D=256, K=8192)
#define N_TOK 16384
#define DIM 256
#define KCB 8192
#define BETA_C 0.25f
#define SLAB 4096
#define NSLAB 4
#define NSPLIT 32          // 8192 / 256 cols per block
#define NCHUNK 4           // single bf16 pass: K=256 = 4 chunks of 64
#define MARGIN 4.0f        // exact-rescore margin (~40 sigma of approx-dist error)

typedef __attribute__((ext_vector_type(8))) short short8;   // 8 bf16 (4 VGPRs)
typedef __attribute__((ext_vector_type(4))) float f32x4;    // MFMA acc
typedef unsigned short ushort_t;

__device__ __forceinline__ void async_copy16(const void* g, void* l) {
    __builtin_amdgcn_global_load_lds(
        (const __attribute__((address_space(1))) unsigned int*)g,
        (__attribute__((address_space(3))) unsigned int*)l, 16, 0, 0);
}

// top-2 merge with lowest-index tie-break (R4-proven logic)
__device__ __forceinline__ void merge2(float& v1, int& i1, float& v2, int& i2,
                                       float b1, int j1, float b2, int j2) {
    const bool bf_ = (b1 < v1) || (b1 == v1 && j1 < i1);
    const float nv1 = bf_ ? b1 : v1; const int ni1 = bf_ ? j1 : i1;
    const float c = bf_ ? v1 : b1;   const int ci = bf_ ? i1 : j1;
    const float d = bf_ ? b2 : v2;   const int di = bf_ ? j2 : i2;
    const bool ds_ = (d < c) || (d == c && di < ci);
    v1 = nv1; i1 = ni1;
    v2 = ds_ ? d : c; i2 = ds_ ? di : ci;
}

// ---------------- prep: f32 row -> bf16 row (truncation; + norm for emb) --------
template <int WITH_NORM>
__global__ void __launch_bounds__(256)
prep1_kernel(const float* __restrict__ src, ushort_t* __restrict__ dst,
             float* __restrict__ norm, int nrows) {
    const int w = threadIdx.x >> 6, lane = threadIdx.x & 63;
    const int r = blockIdx.x * 4 + w;
    if (r >= nrows) return;
    const float4 v = *reinterpret_cast<const float4*>(src + (size_t)r * DIM + lane * 4);
    const unsigned u0 = __float_as_uint(v.x), u1 = __float_as_uint(v.y);
    const unsigned u2 = __float_as_uint(v.z), u3 = __float_as_uint(v.w);
    *reinterpret_cast<uint2*>(dst + (size_t)r * DIM + lane * 4) =
        make_uint2((u0 >> 16) | (u1 & 0xFFFF0000u), (u2 >> 16) | (u3 & 0xFFFF0000u));
    if (WITH_NORM) {
        float s = v.x * v.x + v.y * v.y + v.z * v.z + v.w * v.w;
#pragma unroll
        for (int o = 32; o > 0; o >>= 1) s += __shfl_down(s, o, 64);
        if (lane == 0) norm[r] = s;
    }
}

// ---------------- W transpose to bf16: WT[e][d] = bf16(W[d][e]) ----------------
__global__ void wt_kernel(const float* __restrict__ W, ushort_t* __restrict__ WT) {
    const int flat = blockIdx.x * 256 + threadIdx.x;
    const int d = flat >> 8, e = flat & 255;
    WT[(size_t)e * 256 + d] = (ushort_t)(__float_as_uint(W[flat]) >> 16);
}

// ---------------- pipelined MFMA distance GEMM (256x256 tile, K=256) ------------
// Block: 256 slab rows x 256 codes, single bf16 pass (4 chunks of 64).
// dist = ||e||^2 - 2*x.e (row-const ||x||^2 dropped; enorm exact f32).
// Sync structure identical to R7 (proven); only the chunk count changed.
__global__ void __launch_bounds__(512, 1)
dist_kernel(const ushort_t* __restrict__ X2, const ushort_t* __restrict__ E2,
            const float* __restrict__ enorm, uint4* __restrict__ mg) {
    __shared__ char sb[131072];   // A: [buf][256][128B] @0/32K; B: @64K/96K

    const int tid = threadIdx.x;
    const int lane = tid & 63;
    const int w = tid >> 6;             // 0..7
    const int wy = w >> 2, wx = w & 3;  // 2x4 wave grid; wave tile 128x64
    const int l15 = lane & 15, l4 = lane >> 4;
    const int rr = lane >> 3, egr = (lane & 7) ^ rr;  // pre-swizzled source granule

    // XCD-chunked bijective swizzle of 512 blocks (16 row x 32 col)
    const int bid = blockIdx.x;
    const int sw = (bid & 7) * 64 + (bid >> 3);
    const int bx = sw & 15, by = sw >> 4;
    const int row0 = bx * 256;          // slab-local token row
    const int col0 = by * 256;          // global code col

    const ushort_t* Asrc = X2 + (size_t)(row0 + rr) * DIM + egr * 8;
    const ushort_t* Bsrc = E2 + (size_t)(col0 + rr) * DIM + egr * 8;

    // per-thread swizzled ds_read base offsets; frag adds m*2048 (16 rows)
    int offA[2], offB[2];
#pragma unroll
    for (int ks = 0; ks < 2; ++ks) {
        offA[ks] = (wy * 128 + l15) * 128 + ((ks * 64 + l4 * 16) ^ ((l15 & 7) << 4));
        offB[ks] = (wx * 64 + l15) * 128 + ((ks * 64 + l4 * 16) ^ ((l15 & 7) << 4));
    }

    f32x4 acc[8][4];
#pragma unroll
    for (int m = 0; m < 8; ++m)
#pragma unroll
        for (int n = 0; n < 4; ++n) { f32x4 z = {0.f, 0.f, 0.f, 0.f}; acc[m][n] = z; }

    // chunk sidx (0..3) covers d-range [sidx*64, sidx*64+64)
    auto stage = [&](int sidx, int buf_) {
        const int off = sidx * 64;
#pragma unroll
        for (int i = 0; i < 4; ++i) {
            const int g = w * 4 + i;    // 8-row granule
            async_copy16(Asrc + (size_t)g * 2048 + off, sb + buf_ * 32768 + g * 1024);
            async_copy16(Bsrc + (size_t)g * 2048 + off, sb + 65536 + buf_ * 32768 + g * 1024);
        }
    };

    // prologue: chunks 0,1 in flight; wait own chunk-0 loads (in-order retire)
    stage(0, 0);
    stage(1, 1);
    asm volatile("s_waitcnt vmcnt(8)" ::: "memory");
    __builtin_amdgcn_s_barrier();

#pragma unroll
    for (int s = 0; s < NCHUNK; ++s) {
        const int buf = s & 1;
        const char* Al = sb + buf * 32768;
        const char* Bl = sb + 65536 + buf * 32768;

        // B-frags (8 b128, held all step) + A phase-0 frags (4 b128)
        short8 bfr[4][2], a_cur[2][2], a_nxt[2][2];
#pragma unroll
        for (int n = 0; n < 4; ++n)
#pragma unroll
            for (int ks = 0; ks < 2; ++ks)
                bfr[n][ks] = *reinterpret_cast<const short8*>(Bl + offB[ks] + n * 2048);
#pragma unroll
        for (int mi = 0; mi < 2; ++mi)
#pragma unroll
            for (int ks = 0; ks < 2; ++ks)
                a_cur[mi][ks] = *reinterpret_cast<const short8*>(Al + offA[ks] + mi * 2048);

#pragma unroll
        for (int q = 0; q < 4; ++q) {
            if (q < 3) {
#pragma unroll
                for (int mi = 0; mi < 2; ++mi)
#pragma unroll
                    for (int ks = 0; ks < 2; ++ks)
                        a_nxt[mi][ks] = *reinterpret_cast<const short8*>(
                            Al + offA[ks] + ((q + 1) * 2 + mi) * 2048);
                asm volatile("s_waitcnt lgkmcnt(4)" ::: "memory");  // B + A(q) done
            } else {
                asm volatile("s_waitcnt lgkmcnt(0)" ::: "memory");
            }
            __builtin_amdgcn_sched_barrier(0);

            if (q == 3) {
                // all waves' reads of buf are complete -> safe to restage it
                __builtin_amdgcn_s_barrier();
                if (s + 2 < NCHUNK) stage(s + 2, buf);
                __builtin_amdgcn_sched_barrier(0);
            }

            __builtin_amdgcn_s_setprio(1);
#pragma unroll
            for (int ks = 0; ks < 2; ++ks)
#pragma unroll
                for (int mi = 0; mi < 2; ++mi)
#pragma unroll
                    for (int n = 0; n < 4; ++n)
                        acc[q * 2 + mi][n] = __builtin_amdgcn_mfma_f32_16x16x32_bf16(
                            a_cur[mi][ks], bfr[n][ks], acc[q * 2 + mi][n], 0, 0, 0);
            __builtin_amdgcn_s_setprio(0);
            __builtin_amdgcn_sched_barrier(0);

            if (q < 3) {
#pragma unroll
                for (int mi = 0; mi < 2; ++mi)
#pragma unroll
                    for (int ks = 0; ks < 2; ++ks)
                        a_cur[mi][ks] = a_nxt[mi][ks];   // SSA rename, no copy cost
            }
        }

        // counted wait: retire chunk s+1's loads, keep chunk s+2's in flight
        if (s == NCHUNK - 2) asm volatile("s_waitcnt vmcnt(0)" ::: "memory");
        else if (s < NCHUNK - 2) asm volatile("s_waitcnt vmcnt(8)" ::: "memory");
        __builtin_amdgcn_s_barrier();
    }

    // ---- epilogue: dist, per-row top-2 over the block's 256 cols ----
    float en[4];
#pragma unroll
    for (int n = 0; n < 4; ++n) en[n] = enorm[col0 + wx * 64 + n * 16 + l15];

    uint4* sm2 = reinterpret_cast<uint4*>(sb);   // [wx][256 rows], 16 KB
#pragma unroll
    for (int m = 0; m < 8; ++m)
#pragma unroll
        for (int j = 0; j < 4; ++j) {
            float v1 = FLT_MAX, v2 = FLT_MAX;
            int i1 = 0x7fffffff, i2 = 0x7fffffff;
#pragma unroll
            for (int n = 0; n < 4; ++n) {
                const float v = fmaf(-2.f, acc[m][n][j], en[n]);
                const int kg = col0 + wx * 64 + n * 16 + l15;
                if (v < v1) { v2 = v1; i2 = i1; v1 = v; i1 = kg; }
                else if (v < v2) { v2 = v; i2 = kg; }
            }
#pragma unroll
            for (int o = 1; o < 16; o <<= 1) {
                const float b1 = __shfl_xor(v1, o, 64), b2 = __shfl_xor(v2, o, 64);
                const int j1 = __shfl_xor(i1, o, 64), j2 = __shfl_xor(i2, o, 64);
                merge2(v1, i1, v2, i2, b1, j1, b2, j2);
            }
            if (l15 == 0) {
                const int row = wy * 128 + m * 16 + l4 * 4 + j;
                sm2[wx * 256 + row] = make_uint4(__float_as_uint(v1), (unsigned)i1,
                                                 __float_as_uint(v2), (unsigned)i2);
            }
        }
    __syncthreads();
    if (tid < 256) {
        float v1 = FLT_MAX, v2 = FLT_MAX;
        int i1 = 0x7fffffff, i2 = 0x7fffffff;
#pragma unroll
        for (int wx2 = 0; wx2 < 4; ++wx2) {
            const uint4 q = sm2[wx2 * 256 + tid];
            merge2(v1, i1, v2, i2, __uint_as_float(q.x), (int)q.y,
                   __uint_as_float(q.z), (int)q.w);
        }
        mg[(size_t)(row0 + tid) * NSPLIT + by] =
            make_uint4(__float_as_uint(v1), (unsigned)i1, __float_as_uint(v2), (unsigned)i2);
    }
}

// ---------------- merge stripes + margin-based exact f32 rescore ----------------
// One wave per row: 64 candidates (32 stripes x top-2) in 64 lanes; exact-rescore
// every candidate within MARGIN of the approx min; argmin with lowest-index tie.
__global__ void __launch_bounds__(256)
merge_fixup_kernel(const float* __restrict__ x, const float* __restrict__ emb,
                   const uint4* __restrict__ mg, int* __restrict__ idx_out,
                   float* __restrict__ minq, int row_base) {
    const int w = threadIdx.x >> 6, lane = threadIdx.x & 63;
    const int nl = blockIdx.x * 4 + w;    // slab-local row
    const int n = row_base + nl;          // global row
    const uint4 q = mg[(size_t)nl * NSPLIT + (lane & 31)];
    const float v = (lane < 32) ? __uint_as_float(q.x) : __uint_as_float(q.z);
    const int ki = (lane < 32) ? (int)q.y : (int)q.w;

    // wave-min of approx dist
    float m = v;
#pragma unroll
    for (int o = 1; o < 64; o <<= 1) m = fminf(m, __shfl_xor(m, o, 64));

    const unsigned long long mask = __ballot(v <= m + MARGIN);
    const float4 xv = *reinterpret_cast<const float4*>(x + (size_t)n * DIM + lane * 4);

    float bestv = FLT_MAX;
    int bestk = 0x7fffffff;
    unsigned long long mm = mask;
    while (mm) {
        const int src = __ffsll((long long)mm) - 1;
        mm &= mm - 1;
        const int k = __shfl(ki, src, 64);
        const float4 ev = *reinterpret_cast<const float4*>(emb + (size_t)k * DIM + lane * 4);
        const float dx = xv.x - ev.x, dy = xv.y - ev.y, dz = xv.z - ev.z, dw = xv.w - ev.w;
        float s = dx * dx + dy * dy + dz * dz + dw * dw;
#pragma unroll
        for (int o = 32; o > 0; o >>= 1) s += __shfl_xor(s, o, 64);
        if (s < bestv || (s == bestv && k < bestk)) { bestv = s; bestk = k; }
    }
    if (lane == 0) {
        idx_out[n] = bestk;
        minq[n] = bestv;
    }
}

// ---------------- fused MLP: z = e + W2T-gemm(relu(W1T-gemm(x-e)+b1))+b2 --------
// (R4-proven) Block: 64 rows, 4 waves; h lives only in LDS (bf16).
__global__ void __launch_bounds__(256)
fused_mlp_kernel(const float* __restrict__ x, const float* __restrict__ emb,
                 const int* __restrict__ idx, const ushort_t* __restrict__ W1T,
                 const ushort_t* __restrict__ W2T, const float* __restrict__ b1,
                 const float* __restrict__ b2, float* __restrict__ z) {
    __shared__ char sb[65536];
    __shared__ int idxs[64];

    const int tid = threadIdx.x;
    const int lane = tid & 63;
    const int w = tid >> 6;
    const int l15 = lane & 15, l4 = lane >> 4;
    const int rr = lane >> 3;
    const int egr = (lane & 7) ^ rr;
    const int row0 = blockIdx.x * 64;

    if (tid < 64) idxs[tid] = idx[row0 + tid];
    __syncthreads();

#pragma unroll
    for (int j = 0; j < 16; ++j) {
        const int flat = tid + 256 * j;
        const int r = flat >> 6;
        const int sg = flat & 63;
        const float4 xv = *reinterpret_cast<const float4*>(x + (size_t)(row0 + r) * DIM + sg * 4);
        const float4 ev = *reinterpret_cast<const float4*>(emb + (size_t)idxs[r] * DIM + sg * 4);
        const unsigned u0 = __float_as_uint(xv.x - ev.x), u1 = __float_as_uint(xv.y - ev.y);
        const unsigned u2 = __float_as_uint(xv.z - ev.z), u3 = __float_as_uint(xv.w - ev.w);
        const uint2 pk = make_uint2((u0 >> 16) | (u1 & 0xFFFF0000u),
                                    (u2 >> 16) | (u3 & 0xFFFF0000u));
        *reinterpret_cast<uint2*>(sb + r * 512 + ((sg * 8) ^ ((r & 7) << 4))) = pk;
    }

    const ushort_t* Wp[2] = {W1T, W2T};
    f32x4 acc[4][4];

    for (int layer = 0; layer < 2; ++layer) {
        const ushort_t* WT = Wp[layer];
#pragma unroll
        for (int m = 0; m < 4; ++m)
#pragma unroll
            for (int n = 0; n < 4; ++n) {
                f32x4 zz = {0.f, 0.f, 0.f, 0.f};
                acc[m][n] = zz;
            }
        for (int kc = 0; kc < 4; ++kc) {
            __syncthreads();
#pragma unroll
            for (int i = 0; i < 8; ++i) {
                const int g = w * 8 + i;
                async_copy16(WT + (size_t)(g * 8 + rr) * 256 + kc * 64 + egr * 8,
                             sb + 32768 + g * 1024);
            }
            __syncthreads();
#pragma unroll
            for (int ks = 0; ks < 2; ++ks) {
                short8 af[4], bf[4];
#pragma unroll
                for (int m = 0; m < 4; ++m) {
                    const int r = m * 16 + l15;
                    af[m] = *reinterpret_cast<const short8*>(
                        sb + r * 512 + ((((kc * 2 + ks) * 64) + l4 * 16) ^ ((r & 7) << 4)));
                }
#pragma unroll
                for (int n = 0; n < 4; ++n) {
                    const int r = w * 64 + n * 16 + l15;
                    bf[n] = *reinterpret_cast<const short8*>(
                        sb + 32768 + r * 128 + ((ks * 64 + l4 * 16) ^ ((r & 7) << 4)));
                }
#pragma unroll
                for (int m = 0; m < 4; ++m)
#pragma unroll
                    for (int n = 0; n < 4; ++n)
                        acc[m][n] = __builtin_amdgcn_mfma_f32_16x16x32_bf16(af[m], bf[n], acc[m][n], 0, 0, 0);
            }
        }

        if (layer == 0) {
            float b1v[4];
#pragma unroll
            for (int n = 0; n < 4; ++n) b1v[n] = b1[w * 64 + n * 16 + l15];
            __syncthreads();
#pragma unroll
            for (int m = 0; m < 4; ++m)
#pragma unroll
                for (int n = 0; n < 4; ++n)
#pragma unroll
                    for (int j = 0; j < 4; ++j) {
                        const int row = m * 16 + l4 * 4 + j;
                        const int col = w * 64 + n * 16 + l15;
                        const float hv = fmaxf(acc[m][n][j] + b1v[n], 0.f);
                        *reinterpret_cast<ushort_t*>(
                            sb + row * 512 + ((col * 2) ^ ((row & 7) << 4))) =
                            (ushort_t)(__float_as_uint(hv) >> 16);
                    }
            __syncthreads();
        } else {
            float b2v[4];
#pragma unroll
            for (int n = 0; n < 4; ++n) b2v[n] = b2[w * 64 + n * 16 + l15];
#pragma unroll
            for (int m = 0; m < 4; ++m)
#pragma unroll
                for (int n = 0; n < 4; ++n)
#pragma unroll
                    for (int j = 0; j < 4; ++j) {
                        const int row = m * 16 + l4 * 4 + j;
                        const int col = w * 64 + n * 16 + l15;
                        const float ev = emb[(size_t)idxs[row] * DIM + col];
                        z[(size_t)(row0 + row) * DIM + col] = acc[m][n][j] + b2v[n] + ev;
                    }
        }
    }
}

// ---------------- loss: BETA * mean(exact min dist) ----------------
__global__ void loss_kernel(const float* __restrict__ minq, float* __restrict__ loss_out) {
    const int tid = threadIdx.x;
    float s = 0.f;
    for (int i = tid; i < N_TOK; i += 256) s += minq[i];
#pragma unroll
    for (int o = 32; o > 0; o >>= 1) s += __shfl_down(s, o, 64);
    __shared__ float sbf[4];
    if ((tid & 63) == 0) sbf[tid >> 6] = s;
    __syncthreads();
    if (tid == 0) loss_out[0] = BETA_C * ((sbf[0] + sbf[1] + sbf[2] + sbf[3]) / (float)N_TOK);
}

extern "C" void kernel_launch(void* const* d_in, const int* in_sizes, int n_in,
                              void* d_out, int out_size, void* d_ws, size_t ws_size,
                              hipStream_t stream) {
    const float* x   = (const float*)d_in[0];
    const float* emb = (const float*)d_in[1];
    const float* W1  = (const float*)d_in[2];
    const float* b1  = (const float*)d_in[3];
    const float* W2  = (const float*)d_in[4];
    const float* b2  = (const float*)d_in[5];

    float* z_out = (float*)d_out;
    float* loss_out = z_out + (size_t)N_TOK * DIM;

    // workspace (all disjoint; well under the proven 17.0 MB budget):
    //   [0,32K) enorm | [32K,96K) idx | [96K,160K) minq
    //   [160K,288K) W1T | [288K,416K) W2T
    //   [448K, +4M)  E2 [8192][256] bf16
    //   [8847360, +2M) X2 [4096][256] bf16 slab
    //   [13041664, +2M) mg [4096][32] uint4
    char* ws = (char*)d_ws;
    float*    enorm = (float*)(ws);
    int*      idxb  = (int*)(ws + 32768);
    float*    minq  = (float*)(ws + 98304);
    ushort_t* W1T   = (ushort_t*)(ws + 163840);
    ushort_t* W2T   = (ushort_t*)(ws + 294912);
    ushort_t* E2    = (ushort_t*)(ws + 458752);
    ushort_t* X2    = (ushort_t*)(ws + 8847360);
    uint4*    mg    = (uint4*)(ws + 13041664);

    hipLaunchKernelGGL((prep1_kernel<1>), dim3(KCB / 4), dim3(256), 0, stream,
                       emb, E2, enorm, KCB);
    hipLaunchKernelGGL(wt_kernel, dim3(256), dim3(256), 0, stream, W1, W1T);
    hipLaunchKernelGGL(wt_kernel, dim3(256), dim3(256), 0, stream, W2, W2T);
    for (int s = 0; s < NSLAB; ++s) {
        hipLaunchKernelGGL((prep1_kernel<0>), dim3(SLAB / 4), dim3(256), 0, stream,
                           x + (size_t)s * SLAB * DIM, X2, (float*)nullptr, SLAB);
        hipLaunchKernelGGL(dist_kernel, dim3(512), dim3(512), 0, stream,
                           X2, E2, enorm, mg);
        hipLaunchKernelGGL(merge_fixup_kernel, dim3(SLAB / 4), dim3(256), 0, stream,
                           x, emb, mg, idxb, minq, s * SLAB);
    }
    hipLaunchKernelGGL(fused_mlp_kernel, dim3(N_TOK / 64), dim3(256), 0, stream,
                       x, emb, idxb, W1T, W2T, b1, b2, z_out);
    hipLaunchKernelGGL(loss_kernel, dim3(1), dim3(256), 0, stream, minq, loss_out);
}